// Round 4
// baseline (173.772 us; speedup 1.0000x reference)
//
#include <hip/hip_runtime.h>
#include <hip/hip_bf16.h>

#define B_ 64
#define J_ 2048
#define K_ 32
#define D_ 16
#define KD 512
#define JG 128          // j-groups (spart partial chunks)
#define JC 16           // j's per group
#define BG 16           // b's per block

typedef __attribute__((ext_vector_type(8))) short short8v;   // 8 bf16 (4 VGPR)
typedef __attribute__((ext_vector_type(4))) float f32x4;     // 4 f32 acc

__device__ __forceinline__ float bf2f(unsigned int bits16) {
  unsigned int u = bits16 << 16;
  return __builtin_bit_cast(float, u);
}
__device__ __forceinline__ unsigned int f2bf(float f) {
  unsigned int u = __builtin_bit_cast(unsigned int, f);
  u = u + 0x7fffu + ((u >> 16) & 1u);   // round-to-nearest-even
  return u >> 16;
}

// ---------------- fused sweep: per j, u-tile [512 kd x 16 b] via MFMA (round-3-proven
// mapping), then route. grid (JG, 4). 4 waves; wave owns kd in [128w,128w+128) i.e.
// k in [8w, 8w+8), all 16 b (b = b0 + (lane&15)).
// MODE 0: c = 1/32 -> accumulate MFMA acc directly, no LDS, no barriers.
// MODE 1: logits = osum.u. MODE 2: + write c to out.
template <int MODE>
__global__ __launch_bounds__(256) void k_sweep(const float* __restrict__ inp,
                                               const float* __restrict__ W,
                                               const float* __restrict__ osum,
                                               float* __restrict__ spart,
                                               float* __restrict__ outp) {
  const int jg = blockIdx.x;
  const int b0 = blockIdx.y * BG;
  const int t = threadIdx.x;
  const int wave = t >> 6, lane = t & 63;
  const int g = lane >> 4, r = lane & 15;
  const int j0 = jg * JC;

  __shared__ __align__(16) unsigned short u_lds[(MODE >= 1) ? 2 * BG * KD : 64];
  __shared__ float cbuf[(MODE == 2) ? BG * K_ * (JC + 1) : 4];

  // B-frag loader: inputs^T column b = b0 + r, k-slots = i (4g..4g+3), slots 4-7 zero
  auto loadB = [&](int j) {
    const float4 xv = *(const float4*)(inp + ((size_t)(b0 + r) * J_ + j) * 16 + 4 * g);
    short8v f;
    f[0] = (short)f2bf(xv.x); f[1] = (short)f2bf(xv.y);
    f[2] = (short)f2bf(xv.z); f[3] = (short)f2bf(xv.w);
    f[4] = 0; f[5] = 0; f[6] = 0; f[7] = 0;
    return f;
  };
  // A-frag loader: W row kd = wave*128 + tile*16 + r  (k = wave*8+tile, d = r)
  auto loadA = [&](int j, int tile) {
    const float4 wv = *(const float4*)(W + (size_t)(wave * 8 + tile) * (J_ * 256) +
                                       (size_t)j * 256 + r * 16 + 4 * g);
    short8v f;
    f[0] = (short)f2bf(wv.x); f[1] = (short)f2bf(wv.y);
    f[2] = (short)f2bf(wv.z); f[3] = (short)f2bf(wv.w);
    f[4] = 0; f[5] = 0; f[6] = 0; f[7] = 0;
    return f;
  };

  if constexpr (MODE == 0) {
    // ---- c = 1/32: s-partial = (1/32) * sum_j u ; accumulate in MFMA accs directly
    f32x4 acc[8];
#pragma unroll
    for (int tile = 0; tile < 8; ++tile) acc[tile] = (f32x4){0.f, 0.f, 0.f, 0.f};
    for (int jc = 0; jc < JC; ++jc) {
      const int j = j0 + jc;
      const short8v bfr = loadB(j);
#pragma unroll
      for (int tile = 0; tile < 8; ++tile)
        acc[tile] = __builtin_amdgcn_mfma_f32_16x16x32_bf16(loadA(j, tile), bfr, acc[tile], 0, 0, 0);
    }
    // lane holds s[b0+r][kd0+reg], kd0 = wave*128 + tile*16 + g*4
#pragma unroll
    for (int tile = 0; tile < 8; ++tile) {
      const int kd0 = wave * 128 + tile * 16 + g * 4;
      float4 v = make_float4(acc[tile][0], acc[tile][1], acc[tile][2], acc[tile][3]);
      v.x *= (1.f / 32.f); v.y *= (1.f / 32.f); v.z *= (1.f / 32.f); v.w *= (1.f / 32.f);
      *(float4*)(spart + ((size_t)(b0 + r) * JG + jg) * KD + kd0) = v;
    }
    return;
  }

  // ---- MODE 1/2
  float os[4][8];
#pragma unroll
  for (int bb = 0; bb < 4; ++bb)
#pragma unroll
    for (int q = 0; q < 8; ++q)
      os[bb][q] = osum[(size_t)(b0 + wave * 4 + bb) * KD + lane * 8 + q];

  float accS[4][8];
#pragma unroll
  for (int bb = 0; bb < 4; ++bb)
#pragma unroll
    for (int q = 0; q < 8; ++q) accS[bb][q] = 0.f;

  // stage j into buffer buf: 8 MFMAs -> bf16-packed u-tile rows (XOR-swizzled)
  auto stage = [&](int jc, int buf) {
    const int j = j0 + jc;
    const short8v bfr = loadB(j);
#pragma unroll
    for (int tile = 0; tile < 8; ++tile) {
      f32x4 a = __builtin_amdgcn_mfma_f32_16x16x32_bf16(
          loadA(j, tile), bfr, (f32x4){0.f, 0.f, 0.f, 0.f}, 0, 0, 0);
      const int kd0 = wave * 128 + tile * 16 + g * 4;
      const int kd8 = kd0 >> 3;
      const unsigned int lo = f2bf(a[0]) | (f2bf(a[1]) << 16);
      const unsigned int hi = f2bf(a[2]) | (f2bf(a[3]) << 16);
      *(uint2*)&u_lds[buf * (BG * KD) + r * KD + ((kd8 ^ (r & 7)) << 3) + (kd0 & 7)] =
          make_uint2(lo, hi);
    }
  };

  stage(0, 0);
  for (int jc = 0; jc < JC; ++jc) {
    __syncthreads();
    if (jc + 1 < JC) stage(jc + 1, (jc + 1) & 1);   // overlaps with pass-2 below
    const unsigned short* ub = &u_lds[(jc & 1) * (BG * KD)];
#pragma unroll
    for (int bb = 0; bb < 4; ++bb) {
      const int bl = wave * 4 + bb;
      const uint4 cur = *(const uint4*)&ub[bl * KD + ((lane ^ (bl & 7)) << 3)];
      float u[8];
      u[0] = bf2f(cur.x & 0xffffu); u[1] = bf2f(cur.x >> 16);
      u[2] = bf2f(cur.y & 0xffffu); u[3] = bf2f(cur.y >> 16);
      u[4] = bf2f(cur.z & 0xffffu); u[5] = bf2f(cur.z >> 16);
      u[6] = bf2f(cur.w & 0xffffu); u[7] = bf2f(cur.w >> 16);
      float p = 0.f;
#pragma unroll
      for (int q = 0; q < 8; ++q) p = fmaf(os[bb][q], u[q], p);
      p += __shfl_xor(p, 1);                 // full dot for k = lane>>1
      // softmax is shift-invariant; logits here are O(10) -> skip max subtraction
      float e = __expf(p);
      float S = e;
#pragma unroll
      for (int s = 2; s <= 32; s <<= 1) S += __shfl_xor(S, s);
      const float c = e * __builtin_amdgcn_rcpf(S);
      if constexpr (MODE == 2) {
        if (!(lane & 1)) cbuf[(bl * K_ + (lane >> 1)) * (JC + 1) + jc] = c;
      }
#pragma unroll
      for (int q = 0; q < 8; ++q) accS[bb][q] = fmaf(c, u[q], accS[bb][q]);
    }
  }

  // s-partials: lane owns 8 contiguous kd per b -> two float4 stores
#pragma unroll
  for (int bb = 0; bb < 4; ++bb) {
    float* sp = spart + ((size_t)(b0 + wave * 4 + bb) * JG + jg) * KD + lane * 8;
    *(float4*)sp = make_float4(accS[bb][0], accS[bb][1], accS[bb][2], accS[bb][3]);
    *(float4*)(sp + 4) = make_float4(accS[bb][4], accS[bb][5], accS[bb][6], accS[bb][7]);
  }

  if constexpr (MODE == 2) {
    __syncthreads();
    // flush c: row = bl*32 + k ; 16 j's contiguous in out
#pragma unroll
    for (int h = 0; h < 2; ++h) {
      const int row = t + h * 256;
      const float* crow = &cbuf[row * (JC + 1)];
      float* orow = outp + ((size_t)(b0 + (row >> 5)) * K_ + (row & 31)) * 2064 + 16 + j0;
#pragma unroll
      for (int m4 = 0; m4 < 4; ++m4)
        *(float4*)(orow + 4 * m4) =
            make_float4(crow[4 * m4], crow[4 * m4 + 1], crow[4 * m4 + 2], crow[4 * m4 + 3]);
    }
  }
}

// ---------------- SQ: reduce partials -> s, squash -> outputs; accumulate osum.
__global__ __launch_bounds__(256) void k_squash(const float* __restrict__ spart,
                                                float* __restrict__ osum,
                                                float* __restrict__ outp,
                                                int first, int final_) {
  const int t = threadIdx.x;
  const int wave = t >> 6, lane = t & 63;
  const int gw = blockIdx.x * 4 + wave;   // 0..B_*K_-1
  const int b = gw >> 5, k = gw & 31;
  const int d = lane & 15, pg = lane >> 4;
  float s = 0.f;
  for (int p = pg; p < JG; p += 4)
    s += spart[((size_t)b * JG + p) * KD + k * D_ + d];
  s += __shfl_xor(s, 16);
  s += __shfl_xor(s, 32);
  float ss = s * s;
  ss += __shfl_xor(ss, 1); ss += __shfl_xor(ss, 2);
  ss += __shfl_xor(ss, 4); ss += __shfl_xor(ss, 8);
  float scale = (ss / (1.f + ss)) * rsqrtf(ss + 1e-7f);
  float ov = scale * s;
  if (lane < 16) {
    if (final_) {
      outp[((size_t)b * K_ + k) * 2064 + d] = ov;
    } else {
      float prev = first ? 0.f : osum[(b * K_ + k) * D_ + d];
      osum[(b * K_ + k) * D_ + d] = prev + ov;
    }
  }
}

extern "C" void kernel_launch(void* const* d_in, const int* in_sizes, int n_in,
                              void* d_out, int out_size, void* d_ws, size_t ws_size,
                              hipStream_t stream) {
  const float* inp = (const float*)d_in[0];   // [64,2048,16]
  const float* W   = (const float*)d_in[1];   // [32,2048,16,16]
  float* outp = (float*)d_out;                // [64,32,2064]
  char* ws = (char*)d_ws;
  // ws layout: spart (16 MiB) | osum (128 KiB)
  float* spart = (float*)ws;
  float* osum  = (float*)(ws + (size_t)16777216);

  dim3 grid(JG, B_ / BG);
  k_sweep<0><<<grid, 256, 0, stream>>>(inp, W, nullptr, spart, nullptr);
  k_squash<<<B_ * K_ / 4, 256, 0, stream>>>(spart, osum, outp, 1, 0);
  k_sweep<1><<<grid, 256, 0, stream>>>(inp, W, osum, spart, nullptr);
  k_squash<<<B_ * K_ / 4, 256, 0, stream>>>(spart, osum, outp, 0, 0);
  k_sweep<2><<<grid, 256, 0, stream>>>(inp, W, osum, spart, outp);
  k_squash<<<B_ * K_ / 4, 256, 0, stream>>>(spart, osum, outp, 0, 1);
}